// Round 10
// baseline (1136.421 us; speedup 1.0000x reference)
//
#include <hip/hip_runtime.h>
#include <hip/hip_bf16.h>

typedef unsigned short u16;
typedef __attribute__((ext_vector_type(8))) short bf16x8;
typedef __attribute__((ext_vector_type(4))) float f32x4;
typedef __attribute__((ext_vector_type(8))) unsigned short ushort8;

#define FEAT 1024
#define NOUT 16384
#define EPS 1e-6f
#define NT 16            // K-tiles of 64

#define GLOBAL_AS __attribute__((address_space(1)))
#define LDS_AS __attribute__((address_space(3)))

__device__ __forceinline__ void load16_to_lds(const u16* g, u16* l) {
    __builtin_amdgcn_global_load_lds((const GLOBAL_AS void*)g, (LDS_AS void*)l, 16, 0, 0);
}

__device__ __forceinline__ u16 f32_to_bf16_bits(float f) {
    __hip_bfloat16 h = __float2bfloat16(f);
    return *reinterpret_cast<u16*>(&h);
}

__device__ __forceinline__ float bf16_bits_to_f32(u16 b) {
    unsigned u = ((unsigned)b) << 16;
    float f;
    __builtin_memcpy(&f, &u, 4);
    return f;
}

// Build Wb with a baked-in within-64-row permutation:
//   Wb[p] = W_row[ (p & ~63) | ((p&15)<<2) | ((p>>4)&3) ]
// so the 16x16-MFMA epilogue fragment (nj, fr) maps to 4 CONTIGUOUS output
// columns fr*4+nj (coalesced 8B packed stores).
__global__ void wbuild_kernel(const float* __restrict__ w, u16* __restrict__ Wb) {
    const int t  = blockIdx.x * 256 + threadIdx.x;
    const int p  = t >> 7;                      // Wb row (permuted position)
    const int k0 = (t & 127) << 3;
    const int o  = (p & ~63) | ((p & 15) << 2) | ((p >> 4) & 3);  // logical W row
    const int ai = o >> 9;
    const int bi = (o >> 4) & 31;
    const int ci = o & 15;
    const float* A = w + ai * FEAT + k0;
    const float* B = w + (32 + bi) * FEAT + k0;
    const float* C = w + (64 + ci) * FEAT + k0;
    ushort8 r;
#pragma unroll
    for (int j = 0; j < 8; ++j) r[j] = f32_to_bf16_bits(A[j] * B[j] * C[j]);
    *reinterpret_cast<ushort8*>(Wb + (size_t)t * 8) = r;
}

__global__ void xcast_kernel(const float* __restrict__ x, u16* __restrict__ Xb) {
    const int t = blockIdx.x * 256 + threadIdx.x;
    const float4* xv = reinterpret_cast<const float4*>(x) + (size_t)t * 2;
    const float4 f0 = xv[0];
    const float4 f1 = xv[1];
    float vals[8] = {f0.x, f0.y, f0.z, f0.w, f1.x, f1.y, f1.z, f1.w};
    ushort8 r;
#pragma unroll
    for (int j = 0; j < 8; ++j) r[j] = f32_to_bf16_bits(vals[j]);
    *reinterpret_cast<ushort8*>(Xb + (size_t)t * 8) = r;
}

// ---- 256x256 GEMM, producer/consumer wave specialization (9 waves) ----
// Waves 0-7 (512 thr): pure compute, wave tile 128x64 (2 M-halves x 4 N-q).
//   Per K-tile: 24 ds_read_b128 + 64 MFMA + 1 barrier. NO vmem waits.
// Wave 8 (64 thr): pure producer. Per K-tile: issue 64 global_load_lds
//   staging tile t+1 -> nbuf, then s_waitcnt vmcnt(0) (drain hides under
//   consumers' ~2500cyc tile; producer reaches the barrier early), barrier.
// LDS: 2 buffers x (A 256x64 + B 256x64) bf16 = 128 KiB,
// [buf][op][khalf][256 rows][32 cols], 16B chunks XOR-swizzled (source-side).
// Ledger: producer writes nbuf during t (nbuf last read tile t-1, sealed by
// that tile's barrier); tile t's data drained by producer vmcnt(0) BEFORE
// the barrier that opened t (RAW safe). Barrier counts identical both roles.

#define LDSOFF(buf, isB, kh) (((buf) << 15) + ((isB) << 14) + ((kh) << 13))

// Producer stage of one full tile (A+B, both k-halves) = 64 gloads.
// gload j of region (op,kh): lanes write rows j*16+(lane>>2), chunk lane&3;
// source pre-swizzled: kc = (lane&3) ^ ((lane>>3)&3).
#define PSTAGE(tt, bf) do {                                                   \
    const u16* sa = pA + (size_t)(tt) * 64;                                   \
    const u16* sb = pB + (size_t)(tt) * 64;                                   \
    _Pragma("unroll")                                                         \
    for (int j = 0; j < 16; ++j) {                                            \
        load16_to_lds(sa + j * 16 * FEAT,      lds + LDSOFF(bf, 0, 0) + j * 512); \
        load16_to_lds(sa + j * 16 * FEAT + 32, lds + LDSOFF(bf, 0, 1) + j * 512); \
        load16_to_lds(sb + j * 16 * FEAT,      lds + LDSOFF(bf, 1, 0) + j * 512); \
        load16_to_lds(sb + j * 16 * FEAT + 32, lds + LDSOFF(bf, 1, 1) + j * 512); \
    }                                                                         \
} while (0)

#define RD_A(dst, mi, ks, buf) dst = *reinterpret_cast<const bf16x8*>(        \
    lds + LDSOFF(buf, 0, ks) + (wm * 128 + (mi) * 16 + fr) * 32 + ((kg ^ ((fr >> 1) & 3)) << 3))
#define RD_B(dst, nj, ks, buf) dst = *reinterpret_cast<const bf16x8*>(        \
    lds + LDSOFF(buf, 1, ks) + (wn * 64 + (nj) * 16 + fr) * 32 + ((kg ^ ((fr >> 1) & 3)) << 3))

#define BAR() do {                                                            \
    __builtin_amdgcn_sched_barrier(0);                                        \
    __builtin_amdgcn_s_barrier();                                             \
    __builtin_amdgcn_sched_barrier(0);                                        \
} while (0)

// one k-half: 12 ds_reads + 32 MFMA, no fences (compiler emits counted lgkm)
#define CHALF(kh, buf) do {                                                   \
    bf16x8 a0, a1, a2, a3, a4, a5, a6, a7, b0, b1, b2, b3;                    \
    RD_A(a0, 0, kh, buf); RD_A(a1, 1, kh, buf);                               \
    RD_A(a2, 2, kh, buf); RD_A(a3, 3, kh, buf);                               \
    RD_A(a4, 4, kh, buf); RD_A(a5, 5, kh, buf);                               \
    RD_A(a6, 6, kh, buf); RD_A(a7, 7, kh, buf);                               \
    RD_B(b0, 0, kh, buf); RD_B(b1, 1, kh, buf);                               \
    RD_B(b2, 2, kh, buf); RD_B(b3, 3, kh, buf);                               \
    __builtin_amdgcn_s_setprio(1);                                            \
    acc[0][0] = __builtin_amdgcn_mfma_f32_16x16x32_bf16(a0, b0, acc[0][0], 0, 0, 0); \
    acc[0][1] = __builtin_amdgcn_mfma_f32_16x16x32_bf16(a0, b1, acc[0][1], 0, 0, 0); \
    acc[0][2] = __builtin_amdgcn_mfma_f32_16x16x32_bf16(a0, b2, acc[0][2], 0, 0, 0); \
    acc[0][3] = __builtin_amdgcn_mfma_f32_16x16x32_bf16(a0, b3, acc[0][3], 0, 0, 0); \
    acc[1][0] = __builtin_amdgcn_mfma_f32_16x16x32_bf16(a1, b0, acc[1][0], 0, 0, 0); \
    acc[1][1] = __builtin_amdgcn_mfma_f32_16x16x32_bf16(a1, b1, acc[1][1], 0, 0, 0); \
    acc[1][2] = __builtin_amdgcn_mfma_f32_16x16x32_bf16(a1, b2, acc[1][2], 0, 0, 0); \
    acc[1][3] = __builtin_amdgcn_mfma_f32_16x16x32_bf16(a1, b3, acc[1][3], 0, 0, 0); \
    acc[2][0] = __builtin_amdgcn_mfma_f32_16x16x32_bf16(a2, b0, acc[2][0], 0, 0, 0); \
    acc[2][1] = __builtin_amdgcn_mfma_f32_16x16x32_bf16(a2, b1, acc[2][1], 0, 0, 0); \
    acc[2][2] = __builtin_amdgcn_mfma_f32_16x16x32_bf16(a2, b2, acc[2][2], 0, 0, 0); \
    acc[2][3] = __builtin_amdgcn_mfma_f32_16x16x32_bf16(a2, b3, acc[2][3], 0, 0, 0); \
    acc[3][0] = __builtin_amdgcn_mfma_f32_16x16x32_bf16(a3, b0, acc[3][0], 0, 0, 0); \
    acc[3][1] = __builtin_amdgcn_mfma_f32_16x16x32_bf16(a3, b1, acc[3][1], 0, 0, 0); \
    acc[3][2] = __builtin_amdgcn_mfma_f32_16x16x32_bf16(a3, b2, acc[3][2], 0, 0, 0); \
    acc[3][3] = __builtin_amdgcn_mfma_f32_16x16x32_bf16(a3, b3, acc[3][3], 0, 0, 0); \
    acc[4][0] = __builtin_amdgcn_mfma_f32_16x16x32_bf16(a4, b0, acc[4][0], 0, 0, 0); \
    acc[4][1] = __builtin_amdgcn_mfma_f32_16x16x32_bf16(a4, b1, acc[4][1], 0, 0, 0); \
    acc[4][2] = __builtin_amdgcn_mfma_f32_16x16x32_bf16(a4, b2, acc[4][2], 0, 0, 0); \
    acc[4][3] = __builtin_amdgcn_mfma_f32_16x16x32_bf16(a4, b3, acc[4][3], 0, 0, 0); \
    acc[5][0] = __builtin_amdgcn_mfma_f32_16x16x32_bf16(a5, b0, acc[5][0], 0, 0, 0); \
    acc[5][1] = __builtin_amdgcn_mfma_f32_16x16x32_bf16(a5, b1, acc[5][1], 0, 0, 0); \
    acc[5][2] = __builtin_amdgcn_mfma_f32_16x16x32_bf16(a5, b2, acc[5][2], 0, 0, 0); \
    acc[5][3] = __builtin_amdgcn_mfma_f32_16x16x32_bf16(a5, b3, acc[5][3], 0, 0, 0); \
    acc[6][0] = __builtin_amdgcn_mfma_f32_16x16x32_bf16(a6, b0, acc[6][0], 0, 0, 0); \
    acc[6][1] = __builtin_amdgcn_mfma_f32_16x16x32_bf16(a6, b1, acc[6][1], 0, 0, 0); \
    acc[6][2] = __builtin_amdgcn_mfma_f32_16x16x32_bf16(a6, b2, acc[6][2], 0, 0, 0); \
    acc[6][3] = __builtin_amdgcn_mfma_f32_16x16x32_bf16(a6, b3, acc[6][3], 0, 0, 0); \
    acc[7][0] = __builtin_amdgcn_mfma_f32_16x16x32_bf16(a7, b0, acc[7][0], 0, 0, 0); \
    acc[7][1] = __builtin_amdgcn_mfma_f32_16x16x32_bf16(a7, b1, acc[7][1], 0, 0, 0); \
    acc[7][2] = __builtin_amdgcn_mfma_f32_16x16x32_bf16(a7, b2, acc[7][2], 0, 0, 0); \
    acc[7][3] = __builtin_amdgcn_mfma_f32_16x16x32_bf16(a7, b3, acc[7][3], 0, 0, 0); \
    __builtin_amdgcn_s_setprio(0);                                            \
} while (0)

__global__ __launch_bounds__(576, 2) void gemm_kernel(const u16* __restrict__ Xb,
                                                      const u16* __restrict__ Wb,
                                                      u16* __restrict__ Y) {
    __shared__ u16 lds[65536];   // 128 KiB

    const int tid  = threadIdx.x;
    const int lane = tid & 63;
    const int w    = tid >> 6;     // wave 0..8

    // XCD-aware 2D mapping: xcd = bid%8 owns col-blocks [xcd*8, xcd*8+8),
    // walks rows with 4-col inner chunks (W panel L2-resident).
    const int bid = blockIdx.x;            // 0..2047
    const int xcd = bid & 7;
    const int o   = bid >> 3;              // 0..255
    const int cb  = xcd * 8 + (o >> 7) * 4 + (o & 3);  // 0..63
    const int rb  = (o >> 2) & 31;                     // 0..31
    const int brow = rb * 256;
    const int bcol = cb * 256;

    if (w == 8) {
        // ---------------- producer wave ----------------
        const int srow = lane >> 2;                       // 0..15
        const int kc   = (lane & 3) ^ ((lane >> 3) & 3);  // source-side swizzle
        const u16* pA = Xb + (size_t)(brow + srow) * FEAT + kc * 8;
        const u16* pB = Wb + (size_t)(bcol + srow) * FEAT + kc * 8;

        PSTAGE(0, 0);
        asm volatile("s_waitcnt vmcnt(0)" ::: "memory");
        BAR();
        for (int tt = 0; tt < NT - 1; ++tt) {
            PSTAGE(tt + 1, (tt + 1) & 1);
            asm volatile("s_waitcnt vmcnt(0)" ::: "memory");
            BAR();
        }
        return;   // no epilogue work; barrier counts matched
    }

    // ---------------- consumer waves ----------------
    const int wm = w >> 2;       // M-half
    const int wn = w & 3;        // N-quarter
    const int fr = lane & 15;
    const int kg = lane >> 4;

    f32x4 acc[8][4] = {};

    BAR();   // matches producer prologue barrier (tile 0 published)

    for (int tt = 0; tt < NT; ++tt) {
        const int buf = tt & 1;
        CHALF(0, buf);
        CHALF(1, buf);
        if (tt < NT - 1) BAR();
    }

    // ------------- epilogue: packed coalesced bf16 stores -------------
    // fragment (nj, fr) = output col bcol + wn*64 + fr*4 + nj (perm in wbuild)
    const int colbase = bcol + wn * 64 + fr * 4;
#pragma unroll
    for (int mi = 0; mi < 8; ++mi) {
#pragma unroll
        for (int r = 0; r < 4; ++r) {
            const int row = brow + wm * 128 + mi * 16 + kg * 4 + r;
            const unsigned lo = (unsigned)f32_to_bf16_bits(acc[mi][0][r]) |
                                ((unsigned)f32_to_bf16_bits(acc[mi][1][r]) << 16);
            const unsigned hi = (unsigned)f32_to_bf16_bits(acc[mi][2][r]) |
                                ((unsigned)f32_to_bf16_bits(acc[mi][3][r]) << 16);
            uint2 pk; pk.x = lo; pk.y = hi;
            *reinterpret_cast<uint2*>(Y + (size_t)row * 32768 + colbase) = pk;
        }
    }
}

// Per-row scale: read bf16 y row, compute sum-of-squares from it, write fp32
// normalized row in-place over the same 64KB row slot.
__global__ __launch_bounds__(1024) void scale_kernel(const u16* __restrict__ Y,
                                                     float* __restrict__ out) {
    const int row = blockIdx.x;
    const int tid = threadIdx.x;
    const ushort8* yr = reinterpret_cast<const ushort8*>(Y + (size_t)row * 32768);
    const ushort8 v0 = yr[2 * tid];
    const ushort8 v1 = yr[2 * tid + 1];

    float f[16];
#pragma unroll
    for (int j = 0; j < 8; ++j) {
        f[j]     = bf16_bits_to_f32(v0[j]);
        f[8 + j] = bf16_bits_to_f32(v1[j]);
    }
    float ss = 0.f;
#pragma unroll
    for (int j = 0; j < 16; ++j) ss += f[j] * f[j];

#pragma unroll
    for (int off = 1; off < 64; off <<= 1) ss += __shfl_xor(ss, off, 64);
    __shared__ float wss[16];
    if ((tid & 63) == 0) wss[tid >> 6] = ss;
    __syncthreads();
    float tot = 0.f;
#pragma unroll
    for (int i = 0; i < 16; ++i) tot += wss[i];
    const float sc = rsqrtf(tot * (1.0f / (float)NOUT) + EPS);

    float4* orow = reinterpret_cast<float4*>(out + (size_t)row * NOUT) + tid * 4;
#pragma unroll
    for (int q = 0; q < 4; ++q) {
        float4 ov;
        ov.x = f[q * 4 + 0] * sc;
        ov.y = f[q * 4 + 1] * sc;
        ov.z = f[q * 4 + 2] * sc;
        ov.w = f[q * 4 + 3] * sc;
        orow[q] = ov;
    }
}

extern "C" void kernel_launch(void* const* d_in, const int* in_sizes, int n_in,
                              void* d_out, int out_size, void* d_ws, size_t ws_size,
                              hipStream_t stream) {
    const float* x = (const float*)d_in[0];   // (8192,1024) fp32
    const float* w = (const float*)d_in[1];   // (80,1024) fp32
    float* out = (float*)d_out;               // (8192,16384) fp32

    const int M = in_sizes[0] / FEAT;         // 8192

    u16* Wb = (u16*)d_ws;                                      // 32 MiB
    u16* Xb = (u16*)((char*)d_ws + (size_t)NOUT * FEAT * 2);   // 16 MiB

    u16* Y = (u16*)d_out;   // bf16 y in first 32KB of each 64KB out row

    wbuild_kernel<<<(NOUT * (FEAT / 8)) / 256, 256, 0, stream>>>(w, Wb);
    xcast_kernel<<<(M * FEAT / 8) / 256, 256, 0, stream>>>(x, Xb);

    const int nblk = (M / 256) * (NOUT / 256);   // 2048
    gemm_kernel<<<nblk, 576, 0, stream>>>(Xb, Wb, Y);

    scale_kernel<<<M, 1024, 0, stream>>>(Y, out);
}

// Round 11
// 458.848 us; speedup vs baseline: 2.4767x; 2.4767x over previous
//
#include <hip/hip_runtime.h>
#include <hip/hip_bf16.h>

typedef unsigned short u16;
typedef __attribute__((ext_vector_type(8))) short bf16x8;
typedef __attribute__((ext_vector_type(4))) float f32x4;
typedef __attribute__((ext_vector_type(8))) unsigned short ushort8;

#define FEAT 1024
#define NOUT 16384
#define EPS 1e-6f
#define NT 16            // K-tiles of 64

#define GLOBAL_AS __attribute__((address_space(1)))
#define LDS_AS __attribute__((address_space(3)))

__device__ __forceinline__ void load16_to_lds(const u16* g, u16* l) {
    __builtin_amdgcn_global_load_lds((const GLOBAL_AS void*)g, (LDS_AS void*)l, 16, 0, 0);
}

__device__ __forceinline__ u16 f32_to_bf16_bits(float f) {
    __hip_bfloat16 h = __float2bfloat16(f);
    return *reinterpret_cast<u16*>(&h);
}

__device__ __forceinline__ float bf16_bits_to_f32(u16 b) {
    unsigned u = ((unsigned)b) << 16;
    float f;
    __builtin_memcpy(&f, &u, 4);
    return f;
}

// Fused prep: blocks [0, 8192) build Wb (with the epilogue permutation baked
// in: Wb row p holds logical W row (p&~63)|((p&15)<<2)|((p>>4)&3)); blocks
// [8192, 12288) cast x -> bf16.
__global__ void prep_kernel(const float* __restrict__ w, u16* __restrict__ Wb,
                            const float* __restrict__ x, u16* __restrict__ Xb) {
    const int bid = blockIdx.x;
    if (bid < 8192) {
        const int t  = bid * 256 + threadIdx.x;
        const int p  = t >> 7;                      // Wb row (permuted position)
        const int k0 = (t & 127) << 3;
        const int o  = (p & ~63) | ((p & 15) << 2) | ((p >> 4) & 3);
        const int ai = o >> 9;
        const int bi = (o >> 4) & 31;
        const int ci = o & 15;
        const float* A = w + ai * FEAT + k0;
        const float* B = w + (32 + bi) * FEAT + k0;
        const float* C = w + (64 + ci) * FEAT + k0;
        ushort8 r;
#pragma unroll
        for (int j = 0; j < 8; ++j) r[j] = f32_to_bf16_bits(A[j] * B[j] * C[j]);
        *reinterpret_cast<ushort8*>(Wb + (size_t)t * 8) = r;
    } else {
        const int t = (bid - 8192) * 256 + threadIdx.x;
        const float4* xv = reinterpret_cast<const float4*>(x) + (size_t)t * 2;
        const float4 f0 = xv[0];
        const float4 f1 = xv[1];
        float vals[8] = {f0.x, f0.y, f0.z, f0.w, f1.x, f1.y, f1.z, f1.w};
        ushort8 r;
#pragma unroll
        for (int j = 0; j < 8; ++j) r[j] = f32_to_bf16_bits(vals[j]);
        *reinterpret_cast<ushort8*>(Xb + (size_t)t * 8) = r;
    }
}

// ---------------- 256x256 pipelined GEMM, 2 barriers/K-tile ----------------
// (r5 structure - verified best: GEMM ~290us.)
// 512 threads = 8 waves (2 M-halves x 4 N-quarters), wave tile 128x64.
// LDS: 2 buffers x (A 256x64 + B 256x64) bf16 = 128 KiB,
// [buf][op][khalf][256 rows][32 cols], 16B chunks XOR-swizzled via global src.
// Per tile t (lives in buf = t&1), two halves:
//  half k0: stages (t+1).Ak1 (issued FIRST), reads k0 frags + MFMA, stages
//           (t+1).Bk1 -> nbuf; vmcnt(8) publishes THIS tile's k1; barrier.
//  half k1: stages (t+2).Ak0 (issued FIRST), reads k1 frags + MFMA, stages
//           (t+2).Bk0 -> buf (k0 regions dead since before prev barrier);
//           vmcnt(8) publishes NEXT tile's k0; barrier.
// No lgkmcnt(0)/mid-barrier: ds_read->MFMA ordering is data-dependence
// (compiler emits counted lgkmcnt; LDS pipe drains under MFMA).

#define LDSOFF(buf, isB, kh) (((buf) << 15) + ((isB) << 14) + ((kh) << 13))

#define STAGE(isB, tt, kh, buf) do {                                          \
    const u16* g = ((isB) ? gB : gA) + (size_t)(tt) * 64 + (kh) * 32 + w * 32768; \
    u16* l = lds + LDSOFF(buf, isB, kh) + w * 1024;                           \
    load16_to_lds(g, l);                                                      \
    load16_to_lds(g + 16384, l + 512);                                        \
} while (0)

#define RD_A(dst, mi, ks, buf) dst = *reinterpret_cast<const bf16x8*>(        \
    lds + LDSOFF(buf, 0, ks) + (wm * 128 + (mi) * 16 + fr) * 32 + ((kg ^ ((fr >> 1) & 3)) << 3))
#define RD_B(dst, nj, ks, buf) dst = *reinterpret_cast<const bf16x8*>(        \
    lds + LDSOFF(buf, 1, ks) + (wn * 64 + (nj) * 16 + fr) * 32 + ((kg ^ ((fr >> 1) & 3)) << 3))

#define BAR() do {                                                            \
    __builtin_amdgcn_sched_barrier(0);                                        \
    __builtin_amdgcn_s_barrier();                                             \
    __builtin_amdgcn_sched_barrier(0);                                        \
} while (0)

#define MFMAQ(mibase) do {                                                    \
    __builtin_amdgcn_s_setprio(1);                                            \
    _Pragma("unroll")                                                         \
    for (int mi = 0; mi < 4; ++mi) {                                          \
        acc[(mibase)+mi][0] = __builtin_amdgcn_mfma_f32_16x16x32_bf16(a[mi], b[0], acc[(mibase)+mi][0], 0, 0, 0); \
        acc[(mibase)+mi][1] = __builtin_amdgcn_mfma_f32_16x16x32_bf16(a[mi], b[1], acc[(mibase)+mi][1], 0, 0, 0); \
        acc[(mibase)+mi][2] = __builtin_amdgcn_mfma_f32_16x16x32_bf16(a[mi], b[2], acc[(mibase)+mi][2], 0, 0, 0); \
        acc[(mibase)+mi][3] = __builtin_amdgcn_mfma_f32_16x16x32_bf16(a[mi], b[3], acc[(mibase)+mi][3], 0, 0, 0); \
    }                                                                         \
    __builtin_amdgcn_s_setprio(0);                                            \
} while (0)

// half-end counted waits (loads are 2 per STAGE; 8 = 4 stages in flight)
#define WAIT_H1(t) do {                                                       \
    if ((t) == NT - 1) { asm volatile("s_waitcnt vmcnt(0)" ::: "memory"); }   \
    else               { asm volatile("s_waitcnt vmcnt(8)" ::: "memory"); }   \
} while (0)
#define WAIT_H2(t) do {                                                       \
    if ((t) < NT - 2)       { asm volatile("s_waitcnt vmcnt(8)" ::: "memory"); } \
    else if ((t) == NT - 2) { asm volatile("s_waitcnt vmcnt(4)" ::: "memory"); } \
} while (0)

#define HALF(kh, buf, doStage, stT, stKh, stBuf, WAITC) do {                  \
    if (doStage) STAGE(0, stT, stKh, stBuf);                                  \
    RD_A(a[0], 0, kh, buf); RD_A(a[1], 1, kh, buf);                           \
    RD_A(a[2], 2, kh, buf); RD_A(a[3], 3, kh, buf);                           \
    RD_B(b[0], 0, kh, buf); RD_B(b[1], 1, kh, buf);                           \
    RD_B(b[2], 2, kh, buf); RD_B(b[3], 3, kh, buf);                           \
    MFMAQ(0);                                                                 \
    if (doStage) STAGE(1, stT, stKh, stBuf);                                  \
    RD_A(a[0], 4, kh, buf); RD_A(a[1], 5, kh, buf);                           \
    RD_A(a[2], 6, kh, buf); RD_A(a[3], 7, kh, buf);                           \
    MFMAQ(4);                                                                 \
    WAITC;                                                                    \
    BAR();                                                                    \
} while (0)

#define TILE_BODY(t, buf, nbuf) do {                                          \
    HALF(0, buf, (t) < NT - 1, (t) + 1, 1, nbuf, WAIT_H1(t));                 \
    HALF(1, buf, (t) < NT - 2, (t) + 2, 0, buf,  WAIT_H2(t));                 \
} while (0)

__global__ __launch_bounds__(512, 2) void gemm_kernel(const u16* __restrict__ Xb,
                                                      const u16* __restrict__ Wb,
                                                      u16* __restrict__ Y) {
    __shared__ u16 lds[65536];   // 128 KiB

    const int tid  = threadIdx.x;
    const int lane = tid & 63;
    const int w    = tid >> 6;     // wave 0..7
    const int wm   = w >> 2;       // M-half
    const int wn   = w & 3;        // N-quarter
    const int fr   = lane & 15;
    const int kg   = lane >> 4;

    // XCD-aware 2D mapping: xcd = bid%8 owns col-blocks [xcd*8, xcd*8+8),
    // walks rows with 4-col inner chunks (W panel L2-resident).
    const int bid = blockIdx.x;            // 0..2047
    const int xcd = bid & 7;
    const int o   = bid >> 3;              // 0..255
    const int cb  = xcd * 8 + (o >> 7) * 4 + (o & 3);  // 0..63
    const int rb  = (o >> 2) & 31;                     // 0..31
    const int brow = rb * 256;
    const int bcol = cb * 256;

    // per-thread staging source (pre-swizzled global, linear LDS dest)
    const int srow   = lane >> 2;                       // 0..15
    const int kchunk = (lane & 3) ^ ((lane >> 3) & 3);  // phys->logical swizzle
    const u16* gA = Xb + (size_t)(brow + srow) * FEAT + kchunk * 8;
    const u16* gB = Wb + (size_t)(bcol + srow) * FEAT + kchunk * 8;

    f32x4 acc[8][4] = {};
    bf16x8 a[4], b[4];

    // prologue: tile 0 fully (buf0) + tile1 k0 halves (buf1) = 12 loads;
    // vmcnt(8) -> oldest 4 (t0.Ak0 + t0.Bk0) landed before first reads.
    STAGE(0, 0, 0, 0);
    STAGE(1, 0, 0, 0);
    STAGE(0, 0, 1, 0);
    STAGE(1, 0, 1, 0);
    STAGE(0, 1, 0, 1);
    STAGE(1, 1, 0, 1);
    asm volatile("s_waitcnt vmcnt(8)" ::: "memory");
    BAR();

    for (int tt = 0; tt < NT; tt += 2) {
        TILE_BODY(tt, 0, 1);
        TILE_BODY(tt + 1, 1, 0);
    }

    // ------------- epilogue: packed coalesced bf16 stores -------------
    // fragment (nj, fr) = output col bcol + wn*64 + fr*4 + nj (perm in prep)
    const int colbase = bcol + wn * 64 + fr * 4;
#pragma unroll
    for (int mi = 0; mi < 8; ++mi) {
#pragma unroll
        for (int r = 0; r < 4; ++r) {
            const int row = brow + wm * 128 + mi * 16 + kg * 4 + r;
            const unsigned lo = (unsigned)f32_to_bf16_bits(acc[mi][0][r]) |
                                ((unsigned)f32_to_bf16_bits(acc[mi][1][r]) << 16);
            const unsigned hi = (unsigned)f32_to_bf16_bits(acc[mi][2][r]) |
                                ((unsigned)f32_to_bf16_bits(acc[mi][3][r]) << 16);
            uint2 pk; pk.x = lo; pk.y = hi;
            *reinterpret_cast<uint2*>(Y + (size_t)row * 32768 + colbase) = pk;
        }
    }
}

// Per-row scale: read bf16 y row, compute sum-of-squares from it (bf16-
// quantized ss: rel err <=0.4%, far under threshold), write fp32 normalized
// row in-place over the same 64KB row slot (reads consumed before writes).
__global__ __launch_bounds__(1024) void scale_kernel(const u16* __restrict__ Y,
                                                     float* __restrict__ out) {
    const int row = blockIdx.x;
    const int tid = threadIdx.x;
    const ushort8* yr = reinterpret_cast<const ushort8*>(Y + (size_t)row * 32768);
    const ushort8 v0 = yr[2 * tid];
    const ushort8 v1 = yr[2 * tid + 1];

    float f[16];
#pragma unroll
    for (int j = 0; j < 8; ++j) {
        f[j]     = bf16_bits_to_f32(v0[j]);
        f[8 + j] = bf16_bits_to_f32(v1[j]);
    }
    float ss = 0.f;
#pragma unroll
    for (int j = 0; j < 16; ++j) ss += f[j] * f[j];

#pragma unroll
    for (int off = 1; off < 64; off <<= 1) ss += __shfl_xor(ss, off, 64);
    __shared__ float wss[16];
    if ((tid & 63) == 0) wss[tid >> 6] = ss;
    __syncthreads();
    float tot = 0.f;
#pragma unroll
    for (int i = 0; i < 16; ++i) tot += wss[i];
    const float sc = rsqrtf(tot * (1.0f / (float)NOUT) + EPS);

    float4* orow = reinterpret_cast<float4*>(out + (size_t)row * NOUT) + tid * 4;
#pragma unroll
    for (int q = 0; q < 4; ++q) {
        float4 ov;
        ov.x = f[q * 4 + 0] * sc;
        ov.y = f[q * 4 + 1] * sc;
        ov.z = f[q * 4 + 2] * sc;
        ov.w = f[q * 4 + 3] * sc;
        orow[q] = ov;
    }
}

extern "C" void kernel_launch(void* const* d_in, const int* in_sizes, int n_in,
                              void* d_out, int out_size, void* d_ws, size_t ws_size,
                              hipStream_t stream) {
    const float* x = (const float*)d_in[0];   // (8192,1024) fp32
    const float* w = (const float*)d_in[1];   // (80,1024) fp32
    float* out = (float*)d_out;               // (8192,16384) fp32

    u16* Wb = (u16*)d_ws;                                      // 32 MiB
    u16* Xb = (u16*)((char*)d_ws + (size_t)NOUT * FEAT * 2);   // 16 MiB

    u16* Y = (u16*)d_out;   // bf16 y in first 32KB of each 64KB out row

    prep_kernel<<<12288, 256, 0, stream>>>(w, Wb, x, Xb);

    const int nblk = 2048;   // (8192/256) * (16384/256)
    gemm_kernel<<<nblk, 512, 0, stream>>>(Xb, Wb, Y);

    scale_kernel<<<8192, 1024, 0, stream>>>(Y, out);
}